// Round 1
// baseline (9813.276 us; speedup 1.0000x reference)
//
#include <hip/hip_runtime.h>
#include <hip/hip_bf16.h>

#define NB 128
#define LSEQ 512
#define HD 512
#define G3 1536
#define TI 64
#define KC 16
#define MAX_DEPTH 64

// ---------------------------------------------------------------------------
// prep: transpose W_ih, W_hh -> [k][3H], combine biases
// ---------------------------------------------------------------------------
__global__ __launch_bounds__(256) void prep_kernel(
    const float* __restrict__ W_ih, const float* __restrict__ W_hh,
    const float* __restrict__ b_ih, const float* __restrict__ b_hh,
    float* __restrict__ Wt_ih, float* __restrict__ Wt_hh,
    float* __restrict__ bias4)
{
    int idx = blockIdx.x * 256 + threadIdx.x;
    if (idx < HD * G3) {
        int k = idx / G3, g = idx % G3;
        Wt_ih[idx] = W_ih[g * HD + k];
        Wt_hh[idx] = W_hh[g * HD + k];
    }
    if (idx < HD) {
        bias4[idx]        = b_ih[idx]        + b_hh[idx];         // r
        bias4[512 + idx]  = b_ih[512 + idx]  + b_hh[512 + idx];   // z
        bias4[1024 + idx] = b_ih[1024 + idx];                     // n (x side)
        bias4[1536 + idx] = b_hh[1024 + idx];                     // n (h side)
    }
}

// ---------------------------------------------------------------------------
// sched: compute depth of every (n,l), bucket items by depth.
// depth = distance since last is_initial==1 (is_initial applies at step start).
// One block, 128 threads (one per batch row).
// ---------------------------------------------------------------------------
__global__ __launch_bounds__(128) void sched_kernel(
    const int* __restrict__ is_init,
    int* __restrict__ counts_g, int* __restrict__ offsets_g,
    unsigned* __restrict__ items_g)
{
    __shared__ int cnt[LSEQ];
    __shared__ int off[LSEQ];
    int tid = threadIdx.x;
    for (int i = tid; i < LSEQ; i += 128) cnt[i] = 0;
    __syncthreads();
    {
        int d = 0;
        for (int l = 0; l < LSEQ; l++) {
            int ii = is_init[tid * LSEQ + l];
            d = ii ? 0 : (l == 0 ? 0 : d + 1);
            atomicAdd(&cnt[d], 1);
        }
    }
    __syncthreads();
    if (tid == 0) {
        int acc = 0;
        for (int i = 0; i < LSEQ; i++) { off[i] = acc; acc += cnt[i]; }
    }
    __syncthreads();
    for (int i = tid; i < LSEQ; i += 128) {
        counts_g[i] = cnt[i];
        offsets_g[i] = off[i];
        cnt[i] = 0;   // reuse as cursor
    }
    __syncthreads();
    {
        int d = 0;
        for (int l = 0; l < LSEQ; l++) {
            int ii = is_init[tid * LSEQ + l];
            d = ii ? 0 : (l == 0 ? 0 : d + 1);
            int pos = off[d] + atomicAdd(&cnt[d], 1);
            items_g[pos] = (unsigned)((tid << 16) | l);
        }
    }
}

// ---------------------------------------------------------------------------
// phase: process all items at depth d. For each item (n,l):
//   gates = W_ih @ x[n,l] + W_hh @ h_in + biases ; h_new = GRU update
//   h_in: d>0 -> seq[n,l-1]; d==0 -> 0 if reset else h0[n]
// Tile: 64 items x 64 gate-columns per block, 256 threads, 16 items/thread.
// ---------------------------------------------------------------------------
__global__ __launch_bounds__(256) void phase_kernel(
    int d,
    const float* __restrict__ Wt_ih, const float* __restrict__ Wt_hh,
    const float* __restrict__ bias4,
    const int* __restrict__ counts, const int* __restrict__ offsets,
    const unsigned* __restrict__ items,
    const float* __restrict__ inp, const float* __restrict__ h0,
    const int* __restrict__ is_init,
    float* __restrict__ seq)
{
    const int count = counts[d];
    if (count == 0) return;
    const int base = offsets[d];
    const int jb = blockIdx.y;          // 0..7 -> 64 columns each
    const int tid = threadIdx.x;
    const int tx = tid & 63, ty = tid >> 6;
    const int j = jb * 64 + tx;

    __shared__ float xs[KC][68];
    __shared__ float hs[KC][68];

    const int ntiles = (count + TI - 1) / TI;
    for (int tile = blockIdx.x; tile < ntiles; tile += gridDim.x) {
        float ar[16], az[16], anx[16], anh[16];
        {
            float br = bias4[j], bz = bias4[512 + j];
            float bx = bias4[1024 + j], bh = bias4[1536 + j];
            #pragma unroll
            for (int i = 0; i < 16; i++) { ar[i] = br; az[i] = bz; anx[i] = bx; anh[i] = bh; }
        }

        for (int kc = 0; kc < HD; kc += KC) {
            __syncthreads();
            // stage A-tiles: x and h chunks, layout [k][item]
            for (int idx = tid; idx < TI * KC; idx += 256) {
                int k = idx & (KC - 1);
                int it = idx >> 4;
                int g = tile * TI + it;
                float xv = 0.f, hv = 0.f;
                if (g < count) {
                    unsigned w = items[base + g];
                    int n = (int)(w >> 16), l = (int)(w & 0xffff);
                    xv = inp[((size_t)(n * LSEQ + l)) * HD + kc + k];
                    if (d > 0) {
                        hv = seq[((size_t)(n * LSEQ + l - 1)) * HD + kc + k];
                    } else if (!is_init[n * LSEQ + l]) {
                        hv = h0[(size_t)n * HD + kc + k];
                    }
                }
                xs[k][it] = xv;
                hs[k][it] = hv;
            }
            __syncthreads();

            const float* wi = Wt_ih + (size_t)kc * G3;
            const float* wh = Wt_hh + (size_t)kc * G3;
            #pragma unroll 4
            for (int k = 0; k < KC; k++) {
                float wrx = wi[k * G3 + j];
                float wzx = wi[k * G3 + 512 + j];
                float wnx = wi[k * G3 + 1024 + j];
                float wrh = wh[k * G3 + j];
                float wzh = wh[k * G3 + 512 + j];
                float wnh = wh[k * G3 + 1024 + j];
                const float* xk = &xs[k][ty * 16];
                const float* hk = &hs[k][ty * 16];
                #pragma unroll
                for (int i = 0; i < 16; i++) {
                    float xv = xk[i], hv = hk[i];
                    ar[i]  += wrx * xv + wrh * hv;
                    az[i]  += wzx * xv + wzh * hv;
                    anx[i] += wnx * xv;
                    anh[i] += wnh * hv;
                }
            }
        }

        // epilogue: pointwise GRU update, write raw h into seq
        #pragma unroll
        for (int i = 0; i < 16; i++) {
            int g = tile * TI + ty * 16 + i;
            if (g >= count) continue;
            unsigned w = items[base + g];
            int n = (int)(w >> 16), l = (int)(w & 0xffff);
            float hv = 0.f;
            if (d > 0) {
                hv = seq[((size_t)(n * LSEQ + l - 1)) * HD + j];
            } else if (!is_init[n * LSEQ + l]) {
                hv = h0[(size_t)n * HD + j];
            }
            float r = 1.f / (1.f + __expf(-ar[i]));
            float z = 1.f / (1.f + __expf(-az[i]));
            float nn = tanhf(anx[i] + r * anh[i]);
            float hn = (1.f - z) * nn + z * hv;
            seq[((size_t)(n * LSEQ + l)) * HD + j] = hn;
        }
    }
}

// ---------------------------------------------------------------------------
// h_exp broadcast: out2[n,l,:] = seq[n,L-1,:]  (must run BEFORE LN overwrites)
// ---------------------------------------------------------------------------
__global__ __launch_bounds__(256) void hexp_kernel(
    const float* __restrict__ seq, float* __restrict__ out2)
{
    size_t idx = (size_t)blockIdx.x * 256 + threadIdx.x;
    if (idx >= (size_t)NB * LSEQ * HD) return;
    int n = (int)(idx / (LSEQ * HD));
    int j = (int)(idx & (HD - 1));
    out2[idx] = seq[((size_t)n * LSEQ + (LSEQ - 1)) * HD + j];
}

// ---------------------------------------------------------------------------
// LayerNorm in place over seq: out = LN(seq + inp) * gamma + beta
// one block per (n,l) row
// ---------------------------------------------------------------------------
__global__ __launch_bounds__(256) void ln_kernel(
    const float* __restrict__ inp,
    const float* __restrict__ gamma, const float* __restrict__ beta,
    float* __restrict__ seq)
{
    size_t row = blockIdx.x;
    int tid = threadIdx.x;
    const float* yrow = seq + row * HD;
    const float* xrow = inp + row * HD;
    float a = yrow[tid] + xrow[tid];
    float b = yrow[tid + 256] + xrow[tid + 256];
    float s = a + b, ss = a * a + b * b;
    #pragma unroll
    for (int m = 1; m < 64; m <<= 1) {
        s  += __shfl_xor(s, m, 64);
        ss += __shfl_xor(ss, m, 64);
    }
    __shared__ float ps[4], pss[4];
    int w = tid >> 6;
    if ((tid & 63) == 0) { ps[w] = s; pss[w] = ss; }
    __syncthreads();
    s  = ps[0] + ps[1] + ps[2] + ps[3];
    ss = pss[0] + pss[1] + pss[2] + pss[3];
    float mu = s * (1.f / 512.f);
    float var = ss * (1.f / 512.f) - mu * mu;
    float inv = rsqrtf(var + 1e-5f);
    float* orow = seq + row * HD;
    orow[tid]       = (a - mu) * inv * gamma[tid] + beta[tid];
    orow[tid + 256] = (b - mu) * inv * gamma[tid + 256] + beta[tid + 256];
}

// ---------------------------------------------------------------------------
extern "C" void kernel_launch(void* const* d_in, const int* in_sizes, int n_in,
                              void* d_out, int out_size, void* d_ws, size_t ws_size,
                              hipStream_t stream)
{
    const float* inp   = (const float*)d_in[0];
    const float* h0    = (const float*)d_in[1];
    const int*  is_ini = (const int*)d_in[2];
    const float* W_ih  = (const float*)d_in[3];
    const float* W_hh  = (const float*)d_in[4];
    const float* b_ih  = (const float*)d_in[5];
    const float* b_hh  = (const float*)d_in[6];
    const float* gamma = (const float*)d_in[7];
    const float* beta  = (const float*)d_in[8];

    float* out  = (float*)d_out;
    float* seq  = out;                             // first N*L*H: raw h, then LN in place
    float* out2 = out + (size_t)NB * LSEQ * HD;    // h_exp broadcast

    float* Wt_ih = (float*)d_ws;
    float* Wt_hh = Wt_ih + (size_t)HD * G3;
    float* bias4 = Wt_hh + (size_t)HD * G3;
    int* counts  = (int*)(bias4 + 2048);
    int* offsets = counts + LSEQ;
    unsigned* items = (unsigned*)(offsets + LSEQ);
    // total ws use ~6.6 MB

    prep_kernel<<<(HD * G3 + 255) / 256, 256, 0, stream>>>(
        W_ih, W_hh, b_ih, b_hh, Wt_ih, Wt_hh, bias4);

    sched_kernel<<<1, 128, 0, stream>>>(is_ini, counts, offsets, items);

    for (int d = 0; d < MAX_DEPTH; d++) {
        phase_kernel<<<dim3(512, 8), 256, 0, stream>>>(
            d, Wt_ih, Wt_hh, bias4, counts, offsets, items,
            inp, h0, is_ini, seq);
    }

    hexp_kernel<<<(int)(((size_t)NB * LSEQ * HD + 255) / 256), 256, 0, stream>>>(seq, out2);

    ln_kernel<<<NB * LSEQ, 256, 0, stream>>>(inp, gamma, beta, seq);
}